// Round 15
// baseline (811.272 us; speedup 1.0000x reference)
//
#include <hip/hip_runtime.h>
#include <hip/hip_bf16.h>

#define VOCAB 100
#define EDIM  128
#define HDIM  256
#define LDIM  64
#define G3    768
#define TT    128
#define BB    4096
#define LROW  (TT * VOCAB)
#define H_LD  264            // halfs per h-row (256 + 8 pad)
#define ZP_LD 17             // f16x4 units per zp col (16 rows + 1 pad)

typedef float    f32x4 __attribute__((ext_vector_type(4)));
typedef _Float16 f16x8 __attribute__((ext_vector_type(8)));
typedef _Float16 f16x4 __attribute__((ext_vector_type(4)));

__device__ __forceinline__ float sigf(float x) {
    return __builtin_amdgcn_rcpf(1.0f + __expf(-x));
}
__device__ __forceinline__ float tanh_f(float x) {
    return 2.0f * __builtin_amdgcn_rcpf(1.0f + __expf(-2.0f * x)) - 1.0f;
}
__device__ __forceinline__ void barrier_lgkm() {
    asm volatile("s_waitcnt lgkmcnt(0)\n\ts_barrier" ::: "memory");
}
__device__ __forceinline__ unsigned short h2b(_Float16 h) {
    return __builtin_bit_cast(unsigned short, h);
}

// plain B fragment (linear K)
__device__ __forceinline__ f16x8 ld_bfrag(const float* __restrict__ W, int outcol, int ks, int lgrp) {
    const float* p = W + outcol * HDIM + ks * 32 + lgrp * 8;
    float4 a = *(const float4*)p;
    float4 b = *(const float4*)(p + 4);
    f16x8 w = {(_Float16)a.x, (_Float16)a.y, (_Float16)a.z, (_Float16)a.w,
               (_Float16)b.x, (_Float16)b.y, (_Float16)b.z, (_Float16)b.w};
    return w;
}

// B fragment for the K-PERMUTED h layout (R11-verified):
// physical k p -> logical k_log = (p&~31) | ((p&1)<<4) | ((p&31)>>1)
__device__ __forceinline__ f16x8 ld_bfragK(const float* __restrict__ W, int outcol, int ks, int lgrp) {
    const float* p = W + outcol * HDIM + ks * 32 + lgrp * 4;
    float4 f0 = *(const float4*)p;
    float4 f1 = *(const float4*)(p + 16);
    f16x8 w = {(_Float16)f0.x, (_Float16)f1.x, (_Float16)f0.y, (_Float16)f1.y,
               (_Float16)f0.z, (_Float16)f1.z, (_Float16)f0.w, (_Float16)f1.w};
    return w;
}

// ---------------- prep: PT3[v][col] = {xr+bhr, xz+bhz, xn, bhn} (f16x4) ----------------
__global__ void pt_kernel(const float* __restrict__ emb, const float* __restrict__ Wih,
                          const float* __restrict__ bih, const float* __restrict__ bhh,
                          f16x4* __restrict__ PT) {
    int v = blockIdx.x;
    int col = threadIdx.x;               // 0..255
    __shared__ float se[EDIM];
    if (col < EDIM) se[col] = emb[v * EDIM + col];
    __syncthreads();
    const float* wr = Wih + col * EDIM;
    const float* wz = Wih + (col + 256) * EDIM;
    const float* wn = Wih + (col + 512) * EDIM;
    float xr = bih[col]       + bhh[col];
    float xz = bih[col + 256] + bhh[col + 256];
    float xn = bih[col + 512];
    #pragma unroll 4
    for (int e = 0; e < EDIM; ++e) {
        float s = se[e];
        xr += s * wr[e]; xz += s * wz[e]; xn += s * wn[e];
    }
    f16x4 q = {(_Float16)xr, (_Float16)xz, (_Float16)xn, (_Float16)bhh[512 + col]};
    PT[v * 256 + col] = q;
}

// ===================================================================
// ENCODER: 512 thr / 8 waves (R11-verified geometry, K-permuted h).
// Wave owns 32 logical cols x 3 gates = 192 weight VGPRs; packed f16x4
// PT gather (2 loads/row) keeps total demand ~254 <= 256: no spill.
// A-LDS traffic: 64 KB/step (4x less than the 16-wave variant).
// ===================================================================
__global__ __launch_bounds__(512, 2) void enc_kernel(
    const int* __restrict__ x, const f16x4* __restrict__ PT3,
    const float* __restrict__ Whh,
    float* __restrict__ out)
{
    __shared__ _Float16 s_h[2][16 * H_LD];   // 16896 B
    __shared__ int s_tok[16 * TT];           // 8192 B

    const int tid  = threadIdx.x;
    const int lane = tid & 63;
    const int wv   = tid >> 6;               // 0..7
    const int l15  = lane & 15;
    const int lgrp = lane >> 4;
    const int bbase = blockIdx.x * 16;
    const int colb = wv * 32 + l15;          // logical col (cg=0); cg=1 is +16

    for (int i = tid; i < 16 * TT; i += 512) s_tok[i] = x[bbase * TT + i];

    f16x8 Breg[3][2][8];
    #pragma unroll
    for (int g = 0; g < 3; ++g)
        #pragma unroll
        for (int cg = 0; cg < 2; ++cg)
            #pragma unroll
            for (int ks = 0; ks < 8; ++ks)
                Breg[g][cg][ks] = ld_bfragK(Whh, g * 256 + colb + cg * 16, ks, lgrp);

    float hst[4][2];
    #pragma unroll
    for (int j = 0; j < 4; ++j) { hst[j][0] = 0.f; hst[j][1] = 0.f; }

    for (int i = tid; i < 16 * H_LD; i += 512) s_h[0][i] = (_Float16)0.f;
    __syncthreads();

    int tokp[4];
    #pragma unroll
    for (int j = 0; j < 4; ++j) tokp[j] = s_tok[(lgrp * 4 + j) * TT];

    const f32x4 z4 = {0.f, 0.f, 0.f, 0.f};

    #pragma unroll 1
    for (int t = 0; t < TT; ++t) {
        const _Float16* rh = s_h[t & 1];
        _Float16* wh = s_h[(t + 1) & 1];

        // packed gate-input gathers FIRST: latency hides under the MFMA phase
        f16x4 q[4][2];
        #pragma unroll
        for (int j = 0; j < 4; ++j) {
            const f16x4* p = PT3 + tokp[j] * 256 + colb;
            q[j][0] = p[0];
            q[j][1] = p[16];
        }

        f32x4 acc[3][2];
        #pragma unroll
        for (int g = 0; g < 3; ++g) { acc[g][0] = z4; acc[g][1] = z4; }
        #pragma unroll
        for (int ks = 0; ks < 8; ++ks) {
            f16x8 a = *(const f16x8*)(rh + l15 * H_LD + ks * 32 + lgrp * 8);
            #pragma unroll
            for (int g = 0; g < 3; ++g) {
                acc[g][0] = __builtin_amdgcn_mfma_f32_16x16x32_f16(a, Breg[g][0][ks], acc[g][0], 0, 0, 0);
                acc[g][1] = __builtin_amdgcn_mfma_f32_16x16x32_f16(a, Breg[g][1][ks], acc[g][1], 0, 0, 0);
            }
        }

        if (t + 1 < TT) {
            #pragma unroll
            for (int j = 0; j < 4; ++j) tokp[j] = s_tok[(lgrp * 4 + j) * TT + t + 1];
        }

        #pragma unroll
        for (int j = 0; j < 4; ++j) {
            const int row = lgrp * 4 + j;
            unsigned wpack = 0;
            #pragma unroll
            for (int cg = 0; cg < 2; ++cg) {
                f16x4 qq = q[j][cg];
                float rg = sigf(acc[0][cg][j] + (float)qq[0]);
                float zg = sigf(acc[1][cg][j] + (float)qq[1]);
                float n  = tanh_f((float)qq[2] + rg * (acc[2][cg][j] + (float)qq[3]));
                float h  = n + zg * (hst[j][cg] - n);
                hst[j][cg] = h;
                if (t == TT - 1) out[(size_t)(bbase + row) * LROW + colb + cg * 16] = h;
                wpack |= ((unsigned)h2b((_Float16)h)) << (16 * cg);
            }
            *(unsigned*)(wh + row * H_LD + wv * 32 + 2 * l15) = wpack;
        }
        barrier_lgkm();
    }
}

// ===================================================================
// MID (R13/R14-verified): standalone dec prologue. mu/lv -> out,
// z -> h0, zq = {r+bhr, z+bhz, n, bhn} -> ws.
// ===================================================================
__global__ __launch_bounds__(512, 2) void mid_kernel(
    const float* __restrict__ eps,
    const float* __restrict__ mu_W, const float* __restrict__ mu_b,
    const float* __restrict__ lv_W, const float* __restrict__ lv_b,
    const float* __restrict__ di_W, const float* __restrict__ di_b,
    const float* __restrict__ dec_Wih, const float* __restrict__ dec_bih,
    const float* __restrict__ dec_bhh,
    float* __restrict__ out, f16x4* __restrict__ zq_g, float* __restrict__ h0_g)
{
    __shared__ float s_hl[16 * 260];

    const int tid  = threadIdx.x;
    const int bbase = blockIdx.x * 16;

    for (int i = tid; i < 16 * HDIM; i += 512) {
        int m = i >> 8, c = i & 255;
        s_hl[m * 260 + c] = out[(size_t)(bbase + m) * LROW + c];
    }
    __syncthreads();

    float z0 = 0.f, z1 = 0.f;
    {
        const size_t MU_OFF = (size_t)BB * TT * VOCAB;
        const size_t LV_OFF = MU_OFF + (size_t)BB * LDIM;
        #pragma unroll
        for (int oo = 0; oo < 2; ++oo) {
            int o = tid * 2 + oo;
            int m = o >> 6, j = o & 63;
            const float* mwr = mu_W + j * HDIM;
            const float* lwr = lv_W + j * HDIM;
            float am = mu_b[j], al = lv_b[j];
            #pragma unroll 4
            for (int k = 0; k < HDIM; ++k) { float hv = s_hl[m * 260 + k]; am += hv * mwr[k]; al += hv * lwr[k]; }
            size_t bo = (size_t)(bbase + m) * LDIM + j;
            out[MU_OFF + bo] = am;
            out[LV_OFF + bo] = al;
            float zv = am + eps[bo] * __expf(0.5f * al);
            if (oo == 0) z0 = zv; else z1 = zv;
        }
    }
    __syncthreads();
    {
        int o0 = tid * 2;
        s_hl[(o0 >> 6) * 260 + (o0 & 63)] = z0;
        int o1 = o0 + 1;
        s_hl[(o1 >> 6) * 260 + (o1 & 63)] = z1;
    }
    __syncthreads();

    {
        const int gc = tid & 255;
        const int gm2 = tid >> 8;
        float ah[8], ar[8], az[8], an[8];
        float dib = di_b[gc];
        float bir = dec_bih[gc], biz = dec_bih[gc + 256], bin_ = dec_bih[gc + 512];
        #pragma unroll
        for (int i = 0; i < 8; ++i) { ah[i] = dib; ar[i] = bir; az[i] = biz; an[i] = bin_; }
        const float* w0 = di_W + gc * LDIM;
        const float* w1 = dec_Wih + gc * LDIM;
        const float* w2 = dec_Wih + (gc + 256) * LDIM;
        const float* w3 = dec_Wih + (gc + 512) * LDIM;
        #pragma unroll 2
        for (int j = 0; j < LDIM; ++j) {
            float a0 = w0[j], a1 = w1[j], a2 = w2[j], a3 = w3[j];
            #pragma unroll
            for (int i = 0; i < 8; ++i) {
                float q = s_hl[(gm2 + 2 * i) * 260 + j];
                ah[i] += q * a0; ar[i] += q * a1; az[i] += q * a2; an[i] += q * a3;
            }
        }
        float bhr = dec_bhh[gc], bhz = dec_bhh[gc + 256], bhn_c = dec_bhh[gc + 512];
        #pragma unroll
        for (int i = 0; i < 8; ++i) {
            int m = gm2 + 2 * i;
            float th = tanh_f(ah[i]);
            h0_g[(size_t)(bbase + m) * 256 + gc] = th;
            f16x4 q = {(_Float16)(ar[i] + bhr), (_Float16)(az[i] + bhz), (_Float16)an[i], (_Float16)bhn_c};
            zq_g[(size_t)(bbase + m) * 256 + gc] = q;
        }
    }
}

// ===================================================================
// DECODER RNN (R13/R14-verified): 1024 thr / 16 waves, pure GRU loop.
// ===================================================================
__global__ __launch_bounds__(1024, 4) void dec_rnn_kernel(
    const float* __restrict__ dec_Whh,
    const f16x4* __restrict__ zq_g, const float* __restrict__ h0_g,
    _Float16* __restrict__ Hbuf)
{
    __shared__ _Float16 s_hb[2][16 * H_LD];   // 16896 B
    __shared__ f16x4 s_zq[256 * ZP_LD];       // 34816 B

    const int tid  = threadIdx.x;
    const int lane = tid & 63;
    const int wv   = tid >> 6;
    const int l15  = lane & 15;
    const int lgrp = lane >> 4;
    const int bbase = blockIdx.x * 16;
    const int col  = wv * 16 + l15;

    for (int i = tid; i < 16 * HDIM; i += 1024) {
        int row = i >> 8, c = i & 255;
        float hv = h0_g[(size_t)(bbase + row) * 256 + c];
        s_hb[0][row * H_LD + c] = (_Float16)hv;
        s_zq[c * ZP_LD + row] = zq_g[(size_t)(bbase + row) * 256 + c];
    }

    f16x8 Breg[3][8];
    #pragma unroll
    for (int g = 0; g < 3; ++g)
        #pragma unroll
        for (int ks = 0; ks < 8; ++ks)
            Breg[g][ks] = ld_bfrag(dec_Whh, g * 256 + col, ks, lgrp);

    float hst[4];
    #pragma unroll
    for (int j = 0; j < 4; ++j)
        hst[j] = h0_g[(size_t)(bbase + lgrp * 4 + j) * 256 + col];
    __syncthreads();

    const f32x4 z4 = {0.f, 0.f, 0.f, 0.f};
    const int crow = tid >> 6;       // 0..15
    const int cseg = lane;           // 0..63 (8B chunks)
    _Float16* hb = Hbuf + ((size_t)(bbase + crow) * TT) * 256 + cseg * 4;
    const int lread = crow * H_LD + cseg * 4;

    #pragma unroll 1
    for (int t = 0; t < TT; ++t) {
        const _Float16* rh = s_hb[t & 1];
        _Float16* wh = s_hb[(t + 1) & 1];

        f32x4 a0 = z4, a1 = z4, a2 = z4;
        #pragma unroll
        for (int ks = 0; ks < 8; ++ks) {
            f16x8 a = *(const f16x8*)(rh + l15 * H_LD + ks * 32 + lgrp * 8);
            a0 = __builtin_amdgcn_mfma_f32_16x16x32_f16(a, Breg[0][ks], a0, 0, 0, 0);
            a1 = __builtin_amdgcn_mfma_f32_16x16x32_f16(a, Breg[1][ks], a1, 0, 0, 0);
            a2 = __builtin_amdgcn_mfma_f32_16x16x32_f16(a, Breg[2][ks], a2, 0, 0, 0);
        }
        #pragma unroll
        for (int j = 0; j < 4; ++j) {
            const int row = lgrp * 4 + j;
            f16x4 q = s_zq[col * ZP_LD + row];
            float rg = sigf(a0[j] + (float)q[0]);
            float zg = sigf(a1[j] + (float)q[1]);
            float n  = tanh_f((float)q[2] + rg * (a2[j] + (float)q[3]));
            float h  = n + zg * (hst[j] - n);
            hst[j] = h;
            wh[row * H_LD + col] = (_Float16)h;
        }
        barrier_lgkm();
        *(f16x4*)hb = *(const f16x4*)(wh + lread);
        hb += 256;
    }
}

// ===================================================================
// LOGITS GEMM (R10/R13-verified): LDS-staged LINEAR copy-out.
// ===================================================================
__global__ __launch_bounds__(1024, 4) void logits_kernel(
    const _Float16* __restrict__ Hbuf, const float* __restrict__ out_W,
    const float* __restrict__ out_b, float* __restrict__ out)
{
    __shared__ __attribute__((aligned(16))) unsigned char s_outw[VOCAB * 512]; // 51200 B
    __shared__ __attribute__((aligned(16))) float s_ls[256 * 108];             // 110592 B
    const int tid = threadIdx.x, lane = tid & 63, wv = tid >> 6;
    const int l15 = lane & 15, lgrp = lane >> 4;

    for (int idx = tid; idx < VOCAB * HDIM; idx += 1024) {
        int r = idx >> 8, k = idx & 255;
        _Float16 w = (_Float16)out_W[r * 256 + k];
        *(short*)(s_outw + r * 512 + ((2 * k) ^ ((r & 7) << 4))) = __builtin_bit_cast(short, w);
    }
    __syncthreads();

    float ob[7];
    #pragma unroll
    for (int vt = 0; vt < 7; ++vt) {
        int v = vt * 16 + l15;
        ob[vt] = (v < VOCAB) ? out_b[v] : 0.0f;
    }
    const f32x4 z4 = {0.f, 0.f, 0.f, 0.f};

    #pragma unroll 1
    for (int round = 0; round < 2; ++round) {
        size_t mt = (size_t)blockIdx.x * 32 + round * 16 + wv;
        const _Float16* hrow = Hbuf + (mt * 16 + l15) * 256;
        f32x4 acc[7];
        #pragma unroll
        for (int vt = 0; vt < 7; ++vt) acc[vt] = z4;
        #pragma unroll
        for (int ks = 0; ks < 8; ++ks) {
            f16x8 a = *(const f16x8*)(hrow + ks * 32 + lgrp * 8);
            #pragma unroll
            for (int vt = 0; vt < 7; ++vt) {
                int orow = vt * 16 + l15; if (orow > VOCAB - 1) orow = VOCAB - 1;
                f16x8 wo = *(const f16x8*)(s_outw + orow * 512 + ((ks * 64 + lgrp * 16) ^ ((orow & 7) << 4)));
                acc[vt] = __builtin_amdgcn_mfma_f32_16x16x32_f16(a, wo, acc[vt], 0, 0, 0);
            }
        }
        #pragma unroll
        for (int vt = 0; vt < 7; ++vt) {
            int v = vt * 16 + l15;
            if (v < VOCAB) {
                #pragma unroll
                for (int j = 0; j < 4; ++j)
                    s_ls[(wv * 16 + lgrp * 4 + j) * 108 + v] = acc[vt][j] + ob[vt];
            }
        }
        __syncthreads();
        {
            size_t slabM0 = (size_t)blockIdx.x * 512 + round * 256;
            float* gbase = out + slabM0 * VOCAB;
            for (int c = tid; c < 6400; c += 1024) {
                int r = c / 25, cc = (c % 25) * 4;
                f32x4 vch = *(const f32x4*)(s_ls + r * 108 + cc);
                *(f32x4*)(gbase + (size_t)c * 4) = vch;
            }
        }
        __syncthreads();
    }
}

// ===================================================================
// FALLBACK fused decoder (known-passing) — used if ws too small.
// ===================================================================
__global__ __launch_bounds__(1024, 4) void dec_fused_kernel(
    const float* __restrict__ eps,
    const float* __restrict__ mu_W, const float* __restrict__ mu_b,
    const float* __restrict__ lv_W, const float* __restrict__ lv_b,
    const float* __restrict__ di_W, const float* __restrict__ di_b,
    const float* __restrict__ dec_Wih, const float* __restrict__ dec_Whh,
    const float* __restrict__ dec_bih, const float* __restrict__ dec_bhh,
    const float* __restrict__ out_W, const float* __restrict__ out_b,
    float* __restrict__ out)
{
    __shared__ _Float16 s_hb[2][16 * H_LD];
    __shared__ f16x4 s_zp[256 * ZP_LD];
    __shared__ __attribute__((aligned(16))) unsigned char s_outw[VOCAB * 512];
    __shared__ float s_hl[16 * 260];

    const int tid  = threadIdx.x;
    const int lane = tid & 63;
    const int wv   = tid >> 6;
    const int l15  = lane & 15;
    const int lgrp = lane >> 4;
    const int bbase = blockIdx.x * 16;
    const int col  = wv * 16 + l15;

    for (int i = tid; i < 16 * HDIM; i += 1024) {
        int m = i >> 8, c = i & 255;
        s_hl[m * 260 + c] = out[(size_t)(bbase + m) * LROW + c];
    }
    for (int idx = tid; idx < VOCAB * HDIM; idx += 1024) {
        int r = idx >> 8, k = idx & 255;
        _Float16 w = (_Float16)out_W[r * 256 + k];
        *(short*)(s_outw + r * 512 + ((2 * k) ^ ((r & 7) << 4))) = __builtin_bit_cast(short, w);
    }

    f16x8 Breg[3][8];
    #pragma unroll
    for (int g = 0; g < 3; ++g)
        #pragma unroll
        for (int ks = 0; ks < 8; ++ks)
            Breg[g][ks] = ld_bfrag(dec_Whh, g * 256 + col, ks, lgrp);
    __syncthreads();

    float zv;
    {
        const size_t MU_OFF = (size_t)BB * TT * VOCAB;
        const size_t LV_OFF = MU_OFF + (size_t)BB * LDIM;
        int m = tid >> 6, j = tid & 63;
        const float* mwr = mu_W + j * HDIM;
        const float* lwr = lv_W + j * HDIM;
        float am = mu_b[j], al = lv_b[j];
        #pragma unroll 4
        for (int k = 0; k < HDIM; ++k) { float hv = s_hl[m * 260 + k]; am += hv * mwr[k]; al += hv * lwr[k]; }
        size_t bo = (size_t)(bbase + m) * LDIM + j;
        out[MU_OFF + bo] = am;
        out[LV_OFF + bo] = al;
        zv = am + eps[bo] * __expf(0.5f * al);
    }
    __syncthreads();
    { int m = tid >> 6, j = tid & 63; s_hl[m * 260 + j] = zv; }
    __syncthreads();

    float th[4];
    {
        const int gc = tid & 255;
        const int gm = tid >> 8;
        float ah[4], ar[4], az[4], an[4];
        float dib = di_b[gc];
        float bir = dec_bih[gc], biz = dec_bih[gc + 256], bin_ = dec_bih[gc + 512];
        #pragma unroll
        for (int i = 0; i < 4; ++i) { ah[i] = dib; ar[i] = bir; az[i] = biz; an[i] = bin_; }
        const float* w0 = di_W + gc * LDIM;
        const float* w1 = dec_Wih + gc * LDIM;
        const float* w2 = dec_Wih + (gc + 256) * LDIM;
        const float* w3 = dec_Wih + (gc + 512) * LDIM;
        #pragma unroll 2
        for (int j = 0; j < LDIM; ++j) {
            float a0 = w0[j], a1 = w1[j], a2 = w2[j], a3 = w3[j];
            #pragma unroll
            for (int i = 0; i < 4; ++i) {
                float q = s_hl[(gm * 4 + i) * 260 + j];
                ah[i] += q * a0; ar[i] += q * a1; az[i] += q * a2; an[i] += q * a3;
            }
        }
        float bhr = dec_bhh[gc], bhz = dec_bhh[gc + 256];
        __syncthreads();
        #pragma unroll
        for (int i = 0; i < 4; ++i) {
            int r = gm * 4 + i;
            th[i] = tanh_f(ah[i]);
            s_hl[r * 260 + gc] = th[i];
            f16x4 q = {(_Float16)(ar[i] + bhr), (_Float16)(az[i] + bhz), (_Float16)an[i], (_Float16)0.f};
            s_zp[gc * ZP_LD + r] = q;
            s_hb[0][r * H_LD + gc] = (_Float16)th[i];
        }
    }
    __syncthreads();

    float hpr[4];
    #pragma unroll
    for (int j = 0; j < 4; ++j) hpr[j] = s_hl[(lgrp * 4 + j) * 260 + col];

    const float bhn = dec_bhh[512 + col];
    const int vcol = wv * 16 + l15;
    const int orow = (vcol < VOCAB) ? vcol : (VOCAB - 1);
    const float ob = (wv < 7 && vcol < VOCAB) ? out_b[vcol] : 0.0f;
    const f32x4 z4 = {0.f, 0.f, 0.f, 0.f};

    #pragma unroll 1
    for (int t = 0; t < TT; ++t) {
        const _Float16* rh = s_hb[t & 1];
        _Float16* wh = s_hb[(t + 1) & 1];

        f32x4 a0 = z4, a1 = z4, a2 = z4, aco = z4;
        #pragma unroll
        for (int ks = 0; ks < 8; ++ks) {
            f16x8 a = *(const f16x8*)(rh + l15 * H_LD + ks * 32 + lgrp * 8);
            a0 = __builtin_amdgcn_mfma_f32_16x16x32_f16(a, Breg[0][ks], a0, 0, 0, 0);
            a1 = __builtin_amdgcn_mfma_f32_16x16x32_f16(a, Breg[1][ks], a1, 0, 0, 0);
            a2 = __builtin_amdgcn_mfma_f32_16x16x32_f16(a, Breg[2][ks], a2, 0, 0, 0);
            if (wv < 7) {
                f16x8 wo = *(const f16x8*)(s_outw + orow * 512 + ((ks * 64 + lgrp * 16) ^ ((orow & 7) << 4)));
                aco = __builtin_amdgcn_mfma_f32_16x16x32_f16(a, wo, aco, 0, 0, 0);
            }
        }
        if (t > 0 && wv < 7 && vcol < VOCAB) {
            size_t base = (size_t)(bbase + lgrp * 4) * LROW + (size_t)(t - 1) * VOCAB + vcol;
            #pragma unroll
            for (int j = 0; j < 4; ++j) out[base + (size_t)j * LROW] = aco[j] + ob;
        }
        #pragma unroll
        for (int j = 0; j < 4; ++j) {
            const int row = lgrp * 4 + j;
            f16x4 q = s_zp[col * ZP_LD + lgrp * 4 + j];
            float rg = sigf(a0[j] + (float)q[0]);
            float zg = sigf(a1[j] + (float)q[1]);
            float n  = tanh_f((float)q[2] + rg * (a2[j] + bhn));
            float h  = n + zg * (hpr[j] - n);
            hpr[j] = h;
            wh[row * H_LD + col] = (_Float16)h;
        }
        barrier_lgkm();
    }

    if (wv < 7) {
        const _Float16* rh = s_hb[0];
        f32x4 aco = z4;
        #pragma unroll
        for (int ks = 0; ks < 8; ++ks) {
            f16x8 a  = *(const f16x8*)(rh + l15 * H_LD + ks * 32 + lgrp * 8);
            f16x8 wo = *(const f16x8*)(s_outw + orow * 512 + ((ks * 64 + lgrp * 16) ^ ((orow & 7) << 4)));
            aco = __builtin_amdgcn_mfma_f32_16x16x32_f16(a, wo, aco, 0, 0, 0);
        }
        if (vcol < VOCAB) {
            size_t base = (size_t)(bbase + lgrp * 4) * LROW + (size_t)(TT - 1) * VOCAB + vcol;
            #pragma unroll
            for (int j = 0; j < 4; ++j) out[base + (size_t)j * LROW] = aco[j] + ob;
        }
    }
}

extern "C" void kernel_launch(void* const* d_in, const int* in_sizes, int n_in,
                              void* d_out, int out_size, void* d_ws, size_t ws_size,
                              hipStream_t stream) {
    const int*   x       = (const int*)  d_in[0];
    const float* eps     = (const float*)d_in[1];
    const float* emb     = (const float*)d_in[2];
    const float* enc_Wih = (const float*)d_in[3];
    const float* enc_Whh = (const float*)d_in[4];
    const float* enc_bih = (const float*)d_in[5];
    const float* enc_bhh = (const float*)d_in[6];
    const float* mu_W    = (const float*)d_in[7];
    const float* mu_b    = (const float*)d_in[8];
    const float* lv_W    = (const float*)d_in[9];
    const float* lv_b    = (const float*)d_in[10];
    const float* di_W    = (const float*)d_in[11];
    const float* di_b    = (const float*)d_in[12];
    const float* dec_Wih = (const float*)d_in[13];
    const float* dec_Whh = (const float*)d_in[14];
    const float* dec_bih = (const float*)d_in[15];
    const float* dec_bhh = (const float*)d_in[16];
    const float* out_W   = (const float*)d_in[17];
    const float* out_b   = (const float*)d_in[18];
    float* out = (float*)d_out;

    // ws layout: PT3 | zq | h0 | Hbuf
    f16x4* PT3 = (f16x4*)d_ws;                                       // 204800 B
    const size_t ZQ_OFF = 204800;
    const size_t H0_OFF = ZQ_OFF + (size_t)BB * 256 * 8;             // zq: 8 MB
    const size_t HB_OFF = H0_OFF + (size_t)BB * 256 * 4;             // h0: 4 MB
    f16x4*    zq_g = (f16x4*)((char*)d_ws + ZQ_OFF);
    float*    h0_g = (float*)((char*)d_ws + H0_OFF);
    _Float16* Hbuf = (_Float16*)((char*)d_ws + HB_OFF);              // 268.4 MB
    const size_t need = HB_OFF + (size_t)BB * TT * 256 * sizeof(_Float16);

    pt_kernel<<<VOCAB, 256, 0, stream>>>(emb, enc_Wih, enc_bih, enc_bhh, PT3);
    enc_kernel<<<BB / 16, 512, 0, stream>>>(x, PT3, enc_Whh, out);
    if (ws_size >= need) {
        mid_kernel<<<BB / 16, 512, 0, stream>>>(eps, mu_W, mu_b, lv_W, lv_b,
            di_W, di_b, dec_Wih, dec_bih, dec_bhh, out, zq_g, h0_g);
        dec_rnn_kernel<<<BB / 16, 1024, 0, stream>>>(dec_Whh, zq_g, h0_g, Hbuf);
        logits_kernel<<<(BB * TT / 16) / 32, 1024, 0, stream>>>(Hbuf, out_W, out_b, out);
    } else {
        dec_fused_kernel<<<BB / 16, 1024, 0, stream>>>(eps, mu_W, mu_b, lv_W, lv_b,
            di_W, di_b, dec_Wih, dec_Whh, dec_bih, dec_bhh, out_W, out_b, out);
    }
}

// Round 16
// 742.016 us; speedup vs baseline: 1.0933x; 1.0933x over previous
//
#include <hip/hip_runtime.h>
#include <hip/hip_bf16.h>

#define VOCAB 100
#define EDIM  128
#define HDIM  256
#define LDIM  64
#define G3    768
#define TT    128
#define BB    4096
#define LROW  (TT * VOCAB)
#define H_LD  264            // halfs per h-row (256 + 8 pad)
#define ZP_LD 17             // f16x4 units per zp col (16 rows + 1 pad)

typedef float    f32x4 __attribute__((ext_vector_type(4)));
typedef _Float16 f16x8 __attribute__((ext_vector_type(8)));
typedef _Float16 f16x4 __attribute__((ext_vector_type(4)));

__device__ __forceinline__ float sigf(float x) {
    return __builtin_amdgcn_rcpf(1.0f + __expf(-x));
}
__device__ __forceinline__ float tanh_f(float x) {
    return 2.0f * __builtin_amdgcn_rcpf(1.0f + __expf(-2.0f * x)) - 1.0f;
}
__device__ __forceinline__ void barrier_lgkm() {
    asm volatile("s_waitcnt lgkmcnt(0)\n\ts_barrier" ::: "memory");
}

// plain B fragment (linear K)
__device__ __forceinline__ f16x8 ld_bfrag(const float* __restrict__ W, int outcol, int ks, int lgrp) {
    const float* p = W + outcol * HDIM + ks * 32 + lgrp * 8;
    float4 a = *(const float4*)p;
    float4 b = *(const float4*)(p + 4);
    f16x8 w = {(_Float16)a.x, (_Float16)a.y, (_Float16)a.z, (_Float16)a.w,
               (_Float16)b.x, (_Float16)b.y, (_Float16)b.z, (_Float16)b.w};
    return w;
}

// ---------------- prep: PT3[v][col] = {xr+bhr, xz+bhz, xn, bhn} (f16x4; R15-verified) ----------------
__global__ void pt_kernel(const float* __restrict__ emb, const float* __restrict__ Wih,
                          const float* __restrict__ bih, const float* __restrict__ bhh,
                          f16x4* __restrict__ PT) {
    int v = blockIdx.x;
    int col = threadIdx.x;               // 0..255
    __shared__ float se[EDIM];
    if (col < EDIM) se[col] = emb[v * EDIM + col];
    __syncthreads();
    const float* wr = Wih + col * EDIM;
    const float* wz = Wih + (col + 256) * EDIM;
    const float* wn = Wih + (col + 512) * EDIM;
    float xr = bih[col]       + bhh[col];
    float xz = bih[col + 256] + bhh[col + 256];
    float xn = bih[col + 512];
    #pragma unroll 4
    for (int e = 0; e < EDIM; ++e) {
        float s = se[e];
        xr += s * wr[e]; xz += s * wz[e]; xn += s * wn[e];
    }
    f16x4 q = {(_Float16)xr, (_Float16)xz, (_Float16)xn, (_Float16)bhh[512 + col]};
    PT[v * 256 + col] = q;
}

// ===================================================================
// ENCODER (R14 geometry + packed PT3 gather): 1024 thr / 16 waves,
// 16 rows/block. r,z weights in registers (64 VGPRs); n-gate weights
// in LDS (8 KB/wave). Packed f16x4 gather = 4 VMEM loads/thread-step.
// In-loop reg demand ~102 < 128: no spill.
// ===================================================================
__global__ __launch_bounds__(1024, 4) void enc_kernel(
    const int* __restrict__ x, const f16x4* __restrict__ PT3,
    const float* __restrict__ Whh,
    float* __restrict__ out)
{
    __shared__ _Float16 s_h[2][16 * H_LD];                         // 16896 B
    __shared__ int s_tok[16 * TT];                                 // 8192 B
    __shared__ __attribute__((aligned(16))) _Float16 s_w2[16 * 4096]; // 131072 B

    const int tid  = threadIdx.x;
    const int lane = tid & 63;
    const int wv   = tid >> 6;
    const int l15  = lane & 15;
    const int lgrp = lane >> 4;
    const int bbase = blockIdx.x * 16;
    const int col  = wv * 16 + l15;

    for (int i = tid; i < 16 * TT; i += 1024) s_tok[i] = x[bbase * TT + i];

    // r,z gates -> registers
    f16x8 Breg[2][8];
    #pragma unroll
    for (int g = 0; g < 2; ++g)
        #pragma unroll
        for (int ks = 0; ks < 8; ++ks)
            Breg[g][ks] = ld_bfrag(Whh, g * 256 + col, ks, lgrp);
    // n gate -> LDS (per-wave region, own fragments only)
    const int w2base = wv * 4096 + lane * 8;     // shorts
    #pragma unroll
    for (int ks = 0; ks < 8; ++ks) {
        f16x8 w = ld_bfrag(Whh, 512 + col, ks, lgrp);
        *(f16x8*)(s_w2 + w2base + ks * 512) = w;
    }

    float hst[4] = {0.f, 0.f, 0.f, 0.f};

    for (int i = tid; i < 16 * H_LD; i += 1024) s_h[0][i] = (_Float16)0.f;
    __syncthreads();

    int tokp[4];
    #pragma unroll
    for (int j = 0; j < 4; ++j) tokp[j] = s_tok[(lgrp * 4 + j) * TT];

    const f32x4 z4 = {0.f, 0.f, 0.f, 0.f};

    #pragma unroll 1
    for (int t = 0; t < TT; ++t) {
        const _Float16* rh = s_h[t & 1];
        _Float16* wh = s_h[(t + 1) & 1];

        // packed gate-input gathers FIRST: latency hides under the MFMA phase
        f16x4 q[4];
        #pragma unroll
        for (int j = 0; j < 4; ++j) q[j] = PT3[tokp[j] * 256 + col];

        f32x4 a0 = z4, a1 = z4, a2 = z4;
        #pragma unroll
        for (int ks = 0; ks < 8; ++ks) {
            f16x8 a  = *(const f16x8*)(rh + l15 * H_LD + ks * 32 + lgrp * 8);
            f16x8 b2 = *(const f16x8*)(s_w2 + w2base + ks * 512);
            a0 = __builtin_amdgcn_mfma_f32_16x16x32_f16(a, Breg[0][ks], a0, 0, 0, 0);
            a1 = __builtin_amdgcn_mfma_f32_16x16x32_f16(a, Breg[1][ks], a1, 0, 0, 0);
            a2 = __builtin_amdgcn_mfma_f32_16x16x32_f16(a, b2,          a2, 0, 0, 0);
        }

        // prefetch next-step tokens (LDS) while gates run
        if (t + 1 < TT) {
            #pragma unroll
            for (int j = 0; j < 4; ++j) tokp[j] = s_tok[(lgrp * 4 + j) * TT + t + 1];
        }

        #pragma unroll
        for (int j = 0; j < 4; ++j) {
            const int row = lgrp * 4 + j;
            f16x4 qq = q[j];
            float rg = sigf(a0[j] + (float)qq[0]);
            float zg = sigf(a1[j] + (float)qq[1]);
            float n  = tanh_f((float)qq[2] + rg * (a2[j] + (float)qq[3]));
            float h  = n + zg * (hst[j] - n);
            hst[j] = h;
            wh[row * H_LD + col] = (_Float16)h;
            if (t == TT - 1) out[(size_t)(bbase + row) * LROW + col] = h;
        }
        barrier_lgkm();
    }
}

// ===================================================================
// MID (R13/R14-verified): standalone dec prologue. mu/lv -> out,
// z -> h0, zq = {r+bhr, z+bhz, n, bhn} -> ws.
// ===================================================================
__global__ __launch_bounds__(512, 2) void mid_kernel(
    const float* __restrict__ eps,
    const float* __restrict__ mu_W, const float* __restrict__ mu_b,
    const float* __restrict__ lv_W, const float* __restrict__ lv_b,
    const float* __restrict__ di_W, const float* __restrict__ di_b,
    const float* __restrict__ dec_Wih, const float* __restrict__ dec_bih,
    const float* __restrict__ dec_bhh,
    float* __restrict__ out, f16x4* __restrict__ zq_g, float* __restrict__ h0_g)
{
    __shared__ float s_hl[16 * 260];

    const int tid  = threadIdx.x;
    const int bbase = blockIdx.x * 16;

    for (int i = tid; i < 16 * HDIM; i += 512) {
        int m = i >> 8, c = i & 255;
        s_hl[m * 260 + c] = out[(size_t)(bbase + m) * LROW + c];
    }
    __syncthreads();

    float z0 = 0.f, z1 = 0.f;
    {
        const size_t MU_OFF = (size_t)BB * TT * VOCAB;
        const size_t LV_OFF = MU_OFF + (size_t)BB * LDIM;
        #pragma unroll
        for (int oo = 0; oo < 2; ++oo) {
            int o = tid * 2 + oo;
            int m = o >> 6, j = o & 63;
            const float* mwr = mu_W + j * HDIM;
            const float* lwr = lv_W + j * HDIM;
            float am = mu_b[j], al = lv_b[j];
            #pragma unroll 4
            for (int k = 0; k < HDIM; ++k) { float hv = s_hl[m * 260 + k]; am += hv * mwr[k]; al += hv * lwr[k]; }
            size_t bo = (size_t)(bbase + m) * LDIM + j;
            out[MU_OFF + bo] = am;
            out[LV_OFF + bo] = al;
            float zv = am + eps[bo] * __expf(0.5f * al);
            if (oo == 0) z0 = zv; else z1 = zv;
        }
    }
    __syncthreads();
    {
        int o0 = tid * 2;
        s_hl[(o0 >> 6) * 260 + (o0 & 63)] = z0;
        int o1 = o0 + 1;
        s_hl[(o1 >> 6) * 260 + (o1 & 63)] = z1;
    }
    __syncthreads();

    {
        const int gc = tid & 255;
        const int gm2 = tid >> 8;
        float ah[8], ar[8], az[8], an[8];
        float dib = di_b[gc];
        float bir = dec_bih[gc], biz = dec_bih[gc + 256], bin_ = dec_bih[gc + 512];
        #pragma unroll
        for (int i = 0; i < 8; ++i) { ah[i] = dib; ar[i] = bir; az[i] = biz; an[i] = bin_; }
        const float* w0 = di_W + gc * LDIM;
        const float* w1 = dec_Wih + gc * LDIM;
        const float* w2 = dec_Wih + (gc + 256) * LDIM;
        const float* w3 = dec_Wih + (gc + 512) * LDIM;
        #pragma unroll 2
        for (int j = 0; j < LDIM; ++j) {
            float a0 = w0[j], a1 = w1[j], a2 = w2[j], a3 = w3[j];
            #pragma unroll
            for (int i = 0; i < 8; ++i) {
                float q = s_hl[(gm2 + 2 * i) * 260 + j];
                ah[i] += q * a0; ar[i] += q * a1; az[i] += q * a2; an[i] += q * a3;
            }
        }
        float bhr = dec_bhh[gc], bhz = dec_bhh[gc + 256], bhn_c = dec_bhh[gc + 512];
        #pragma unroll
        for (int i = 0; i < 8; ++i) {
            int m = gm2 + 2 * i;
            float th = tanh_f(ah[i]);
            h0_g[(size_t)(bbase + m) * 256 + gc] = th;
            f16x4 q = {(_Float16)(ar[i] + bhr), (_Float16)(az[i] + bhz), (_Float16)an[i], (_Float16)bhn_c};
            zq_g[(size_t)(bbase + m) * 256 + gc] = q;
        }
    }
}

// ===================================================================
// DECODER RNN (R13/R14-verified): 1024 thr / 16 waves, pure GRU loop.
// ===================================================================
__global__ __launch_bounds__(1024, 4) void dec_rnn_kernel(
    const float* __restrict__ dec_Whh,
    const f16x4* __restrict__ zq_g, const float* __restrict__ h0_g,
    _Float16* __restrict__ Hbuf)
{
    __shared__ _Float16 s_hb[2][16 * H_LD];   // 16896 B
    __shared__ f16x4 s_zq[256 * ZP_LD];       // 34816 B

    const int tid  = threadIdx.x;
    const int lane = tid & 63;
    const int wv   = tid >> 6;
    const int l15  = lane & 15;
    const int lgrp = lane >> 4;
    const int bbase = blockIdx.x * 16;
    const int col  = wv * 16 + l15;

    for (int i = tid; i < 16 * HDIM; i += 1024) {
        int row = i >> 8, c = i & 255;
        float hv = h0_g[(size_t)(bbase + row) * 256 + c];
        s_hb[0][row * H_LD + c] = (_Float16)hv;
        s_zq[c * ZP_LD + row] = zq_g[(size_t)(bbase + row) * 256 + c];
    }

    f16x8 Breg[3][8];
    #pragma unroll
    for (int g = 0; g < 3; ++g)
        #pragma unroll
        for (int ks = 0; ks < 8; ++ks)
            Breg[g][ks] = ld_bfrag(dec_Whh, g * 256 + col, ks, lgrp);

    float hst[4];
    #pragma unroll
    for (int j = 0; j < 4; ++j)
        hst[j] = h0_g[(size_t)(bbase + lgrp * 4 + j) * 256 + col];
    __syncthreads();

    const f32x4 z4 = {0.f, 0.f, 0.f, 0.f};
    const int crow = tid >> 6;       // 0..15
    const int cseg = lane;           // 0..63 (8B chunks)
    _Float16* hb = Hbuf + ((size_t)(bbase + crow) * TT) * 256 + cseg * 4;
    const int lread = crow * H_LD + cseg * 4;

    #pragma unroll 1
    for (int t = 0; t < TT; ++t) {
        const _Float16* rh = s_hb[t & 1];
        _Float16* wh = s_hb[(t + 1) & 1];

        f32x4 a0 = z4, a1 = z4, a2 = z4;
        #pragma unroll
        for (int ks = 0; ks < 8; ++ks) {
            f16x8 a = *(const f16x8*)(rh + l15 * H_LD + ks * 32 + lgrp * 8);
            a0 = __builtin_amdgcn_mfma_f32_16x16x32_f16(a, Breg[0][ks], a0, 0, 0, 0);
            a1 = __builtin_amdgcn_mfma_f32_16x16x32_f16(a, Breg[1][ks], a1, 0, 0, 0);
            a2 = __builtin_amdgcn_mfma_f32_16x16x32_f16(a, Breg[2][ks], a2, 0, 0, 0);
        }
        #pragma unroll
        for (int j = 0; j < 4; ++j) {
            const int row = lgrp * 4 + j;
            f16x4 q = s_zq[col * ZP_LD + row];
            float rg = sigf(a0[j] + (float)q[0]);
            float zg = sigf(a1[j] + (float)q[1]);
            float n  = tanh_f((float)q[2] + rg * (a2[j] + (float)q[3]));
            float h  = n + zg * (hst[j] - n);
            hst[j] = h;
            wh[row * H_LD + col] = (_Float16)h;
        }
        barrier_lgkm();
        *(f16x4*)hb = *(const f16x4*)(wh + lread);
        hb += 256;
    }
}

// ===================================================================
// LOGITS GEMM (R10/R13-verified): LDS-staged LINEAR copy-out.
// ===================================================================
__global__ __launch_bounds__(1024, 4) void logits_kernel(
    const _Float16* __restrict__ Hbuf, const float* __restrict__ out_W,
    const float* __restrict__ out_b, float* __restrict__ out)
{
    __shared__ __attribute__((aligned(16))) unsigned char s_outw[VOCAB * 512]; // 51200 B
    __shared__ __attribute__((aligned(16))) float s_ls[256 * 108];             // 110592 B
    const int tid = threadIdx.x, lane = tid & 63, wv = tid >> 6;
    const int l15 = lane & 15, lgrp = lane >> 4;

    for (int idx = tid; idx < VOCAB * HDIM; idx += 1024) {
        int r = idx >> 8, k = idx & 255;
        _Float16 w = (_Float16)out_W[r * 256 + k];
        *(short*)(s_outw + r * 512 + ((2 * k) ^ ((r & 7) << 4))) = __builtin_bit_cast(short, w);
    }
    __syncthreads();

    float ob[7];
    #pragma unroll
    for (int vt = 0; vt < 7; ++vt) {
        int v = vt * 16 + l15;
        ob[vt] = (v < VOCAB) ? out_b[v] : 0.0f;
    }
    const f32x4 z4 = {0.f, 0.f, 0.f, 0.f};

    #pragma unroll 1
    for (int round = 0; round < 2; ++round) {
        size_t mt = (size_t)blockIdx.x * 32 + round * 16 + wv;
        const _Float16* hrow = Hbuf + (mt * 16 + l15) * 256;
        f32x4 acc[7];
        #pragma unroll
        for (int vt = 0; vt < 7; ++vt) acc[vt] = z4;
        #pragma unroll
        for (int ks = 0; ks < 8; ++ks) {
            f16x8 a = *(const f16x8*)(hrow + ks * 32 + lgrp * 8);
            #pragma unroll
            for (int vt = 0; vt < 7; ++vt) {
                int orow = vt * 16 + l15; if (orow > VOCAB - 1) orow = VOCAB - 1;
                f16x8 wo = *(const f16x8*)(s_outw + orow * 512 + ((ks * 64 + lgrp * 16) ^ ((orow & 7) << 4)));
                acc[vt] = __builtin_amdgcn_mfma_f32_16x16x32_f16(a, wo, acc[vt], 0, 0, 0);
            }
        }
        #pragma unroll
        for (int vt = 0; vt < 7; ++vt) {
            int v = vt * 16 + l15;
            if (v < VOCAB) {
                #pragma unroll
                for (int j = 0; j < 4; ++j)
                    s_ls[(wv * 16 + lgrp * 4 + j) * 108 + v] = acc[vt][j] + ob[vt];
            }
        }
        __syncthreads();
        {
            size_t slabM0 = (size_t)blockIdx.x * 512 + round * 256;
            float* gbase = out + slabM0 * VOCAB;
            for (int c = tid; c < 6400; c += 1024) {
                int r = c / 25, cc = (c % 25) * 4;
                f32x4 vch = *(const f32x4*)(s_ls + r * 108 + cc);
                *(f32x4*)(gbase + (size_t)c * 4) = vch;
            }
        }
        __syncthreads();
    }
}

// ===================================================================
// FALLBACK fused decoder (known-passing) — used if ws too small.
// ===================================================================
__global__ __launch_bounds__(1024, 4) void dec_fused_kernel(
    const float* __restrict__ eps,
    const float* __restrict__ mu_W, const float* __restrict__ mu_b,
    const float* __restrict__ lv_W, const float* __restrict__ lv_b,
    const float* __restrict__ di_W, const float* __restrict__ di_b,
    const float* __restrict__ dec_Wih, const float* __restrict__ dec_Whh,
    const float* __restrict__ dec_bih, const float* __restrict__ dec_bhh,
    const float* __restrict__ out_W, const float* __restrict__ out_b,
    float* __restrict__ out)
{
    __shared__ _Float16 s_hb[2][16 * H_LD];
    __shared__ f16x4 s_zp[256 * ZP_LD];
    __shared__ __attribute__((aligned(16))) unsigned char s_outw[VOCAB * 512];
    __shared__ float s_hl[16 * 260];

    const int tid  = threadIdx.x;
    const int lane = tid & 63;
    const int wv   = tid >> 6;
    const int l15  = lane & 15;
    const int lgrp = lane >> 4;
    const int bbase = blockIdx.x * 16;
    const int col  = wv * 16 + l15;

    for (int i = tid; i < 16 * HDIM; i += 1024) {
        int m = i >> 8, c = i & 255;
        s_hl[m * 260 + c] = out[(size_t)(bbase + m) * LROW + c];
    }
    for (int idx = tid; idx < VOCAB * HDIM; idx += 1024) {
        int r = idx >> 8, k = idx & 255;
        _Float16 w = (_Float16)out_W[r * 256 + k];
        *(short*)(s_outw + r * 512 + ((2 * k) ^ ((r & 7) << 4))) = __builtin_bit_cast(short, w);
    }

    f16x8 Breg[3][8];
    #pragma unroll
    for (int g = 0; g < 3; ++g)
        #pragma unroll
        for (int ks = 0; ks < 8; ++ks)
            Breg[g][ks] = ld_bfrag(dec_Whh, g * 256 + col, ks, lgrp);
    __syncthreads();

    float zv;
    {
        const size_t MU_OFF = (size_t)BB * TT * VOCAB;
        const size_t LV_OFF = MU_OFF + (size_t)BB * LDIM;
        int m = tid >> 6, j = tid & 63;
        const float* mwr = mu_W + j * HDIM;
        const float* lwr = lv_W + j * HDIM;
        float am = mu_b[j], al = lv_b[j];
        #pragma unroll 4
        for (int k = 0; k < HDIM; ++k) { float hv = s_hl[m * 260 + k]; am += hv * mwr[k]; al += hv * lwr[k]; }
        size_t bo = (size_t)(bbase + m) * LDIM + j;
        out[MU_OFF + bo] = am;
        out[LV_OFF + bo] = al;
        zv = am + eps[bo] * __expf(0.5f * al);
    }
    __syncthreads();
    { int m = tid >> 6, j = tid & 63; s_hl[m * 260 + j] = zv; }
    __syncthreads();

    float th[4];
    {
        const int gc = tid & 255;
        const int gm = tid >> 8;
        float ah[4], ar[4], az[4], an[4];
        float dib = di_b[gc];
        float bir = dec_bih[gc], biz = dec_bih[gc + 256], bin_ = dec_bih[gc + 512];
        #pragma unroll
        for (int i = 0; i < 4; ++i) { ah[i] = dib; ar[i] = bir; az[i] = biz; an[i] = bin_; }
        const float* w0 = di_W + gc * LDIM;
        const float* w1 = dec_Wih + gc * LDIM;
        const float* w2 = dec_Wih + (gc + 256) * LDIM;
        const float* w3 = dec_Wih + (gc + 512) * LDIM;
        #pragma unroll 2
        for (int j = 0; j < LDIM; ++j) {
            float a0 = w0[j], a1 = w1[j], a2 = w2[j], a3 = w3[j];
            #pragma unroll
            for (int i = 0; i < 4; ++i) {
                float q = s_hl[(gm * 4 + i) * 260 + j];
                ah[i] += q * a0; ar[i] += q * a1; az[i] += q * a2; an[i] += q * a3;
            }
        }
        float bhr = dec_bhh[gc], bhz = dec_bhh[gc + 256];
        __syncthreads();
        #pragma unroll
        for (int i = 0; i < 4; ++i) {
            int r = gm * 4 + i;
            th[i] = tanh_f(ah[i]);
            s_hl[r * 260 + gc] = th[i];
            f16x4 q = {(_Float16)(ar[i] + bhr), (_Float16)(az[i] + bhz), (_Float16)an[i], (_Float16)0.f};
            s_zp[gc * ZP_LD + r] = q;
            s_hb[0][r * H_LD + gc] = (_Float16)th[i];
        }
    }
    __syncthreads();

    float hpr[4];
    #pragma unroll
    for (int j = 0; j < 4; ++j) hpr[j] = s_hl[(lgrp * 4 + j) * 260 + col];

    const float bhn = dec_bhh[512 + col];
    const int vcol = wv * 16 + l15;
    const int orow = (vcol < VOCAB) ? vcol : (VOCAB - 1);
    const float ob = (wv < 7 && vcol < VOCAB) ? out_b[vcol] : 0.0f;
    const f32x4 z4 = {0.f, 0.f, 0.f, 0.f};

    #pragma unroll 1
    for (int t = 0; t < TT; ++t) {
        const _Float16* rh = s_hb[t & 1];
        _Float16* wh = s_hb[(t + 1) & 1];

        f32x4 a0 = z4, a1 = z4, a2 = z4, aco = z4;
        #pragma unroll
        for (int ks = 0; ks < 8; ++ks) {
            f16x8 a = *(const f16x8*)(rh + l15 * H_LD + ks * 32 + lgrp * 8);
            a0 = __builtin_amdgcn_mfma_f32_16x16x32_f16(a, Breg[0][ks], a0, 0, 0, 0);
            a1 = __builtin_amdgcn_mfma_f32_16x16x32_f16(a, Breg[1][ks], a1, 0, 0, 0);
            a2 = __builtin_amdgcn_mfma_f32_16x16x32_f16(a, Breg[2][ks], a2, 0, 0, 0);
            if (wv < 7) {
                f16x8 wo = *(const f16x8*)(s_outw + orow * 512 + ((ks * 64 + lgrp * 16) ^ ((orow & 7) << 4)));
                aco = __builtin_amdgcn_mfma_f32_16x16x32_f16(a, wo, aco, 0, 0, 0);
            }
        }
        if (t > 0 && wv < 7 && vcol < VOCAB) {
            size_t base = (size_t)(bbase + lgrp * 4) * LROW + (size_t)(t - 1) * VOCAB + vcol;
            #pragma unroll
            for (int j = 0; j < 4; ++j) out[base + (size_t)j * LROW] = aco[j] + ob;
        }
        #pragma unroll
        for (int j = 0; j < 4; ++j) {
            const int row = lgrp * 4 + j;
            f16x4 q = s_zp[col * ZP_LD + lgrp * 4 + j];
            float rg = sigf(a0[j] + (float)q[0]);
            float zg = sigf(a1[j] + (float)q[1]);
            float n  = tanh_f((float)q[2] + rg * (a2[j] + bhn));
            float h  = n + zg * (hpr[j] - n);
            hpr[j] = h;
            wh[row * H_LD + col] = (_Float16)h;
        }
        barrier_lgkm();
    }

    if (wv < 7) {
        const _Float16* rh = s_hb[0];
        f32x4 aco = z4;
        #pragma unroll
        for (int ks = 0; ks < 8; ++ks) {
            f16x8 a  = *(const f16x8*)(rh + l15 * H_LD + ks * 32 + lgrp * 8);
            f16x8 wo = *(const f16x8*)(s_outw + orow * 512 + ((ks * 64 + lgrp * 16) ^ ((orow & 7) << 4)));
            aco = __builtin_amdgcn_mfma_f32_16x16x32_f16(a, wo, aco, 0, 0, 0);
        }
        if (vcol < VOCAB) {
            size_t base = (size_t)(bbase + lgrp * 4) * LROW + (size_t)(TT - 1) * VOCAB + vcol;
            #pragma unroll
            for (int j = 0; j < 4; ++j) out[base + (size_t)j * LROW] = aco[j] + ob;
        }
    }
}

extern "C" void kernel_launch(void* const* d_in, const int* in_sizes, int n_in,
                              void* d_out, int out_size, void* d_ws, size_t ws_size,
                              hipStream_t stream) {
    const int*   x       = (const int*)  d_in[0];
    const float* eps     = (const float*)d_in[1];
    const float* emb     = (const float*)d_in[2];
    const float* enc_Wih = (const float*)d_in[3];
    const float* enc_Whh = (const float*)d_in[4];
    const float* enc_bih = (const float*)d_in[5];
    const float* enc_bhh = (const float*)d_in[6];
    const float* mu_W    = (const float*)d_in[7];
    const float* mu_b    = (const float*)d_in[8];
    const float* lv_W    = (const float*)d_in[9];
    const float* lv_b    = (const float*)d_in[10];
    const float* di_W    = (const float*)d_in[11];
    const float* di_b    = (const float*)d_in[12];
    const float* dec_Wih = (const float*)d_in[13];
    const float* dec_Whh = (const float*)d_in[14];
    const float* dec_bih = (const float*)d_in[15];
    const float* dec_bhh = (const float*)d_in[16];
    const float* out_W   = (const float*)d_in[17];
    const float* out_b   = (const float*)d_in[18];
    float* out = (float*)d_out;

    // ws layout: PT3 | zq | h0 | Hbuf
    f16x4* PT3 = (f16x4*)d_ws;                                       // 204800 B
    const size_t ZQ_OFF = 204800;
    const size_t H0_OFF = ZQ_OFF + (size_t)BB * 256 * 8;             // zq: 8 MB
    const size_t HB_OFF = H0_OFF + (size_t)BB * 256 * 4;             // h0: 4 MB
    f16x4*    zq_g = (f16x4*)((char*)d_ws + ZQ_OFF);
    float*    h0_g = (float*)((char*)d_ws + H0_OFF);
    _Float16* Hbuf = (_Float16*)((char*)d_ws + HB_OFF);              // 268.4 MB
    const size_t need = HB_OFF + (size_t)BB * TT * 256 * sizeof(_Float16);

    pt_kernel<<<VOCAB, 256, 0, stream>>>(emb, enc_Wih, enc_bih, enc_bhh, PT3);
    enc_kernel<<<BB / 16, 1024, 0, stream>>>(x, PT3, enc_Whh, out);
    if (ws_size >= need) {
        mid_kernel<<<BB / 16, 512, 0, stream>>>(eps, mu_W, mu_b, lv_W, lv_b,
            di_W, di_b, dec_Wih, dec_bih, dec_bhh, out, zq_g, h0_g);
        dec_rnn_kernel<<<BB / 16, 1024, 0, stream>>>(dec_Whh, zq_g, h0_g, Hbuf);
        logits_kernel<<<(BB * TT / 16) / 32, 1024, 0, stream>>>(Hbuf, out_W, out_b, out);
    } else {
        dec_fused_kernel<<<BB / 16, 1024, 0, stream>>>(eps, mu_W, mu_b, lv_W, lv_b,
            di_W, di_b, dec_Wih, dec_Whh, dec_bih, dec_bhh, out_W, out_b, out);
    }
}

// Round 17
// 731.426 us; speedup vs baseline: 1.1092x; 1.0145x over previous
//
#include <hip/hip_runtime.h>
#include <hip/hip_bf16.h>

#define VOCAB 100
#define EDIM  128
#define HDIM  256
#define LDIM  64
#define G3    768
#define TT    128
#define BB    4096
#define LROW  (TT * VOCAB)
#define H_LD  264            // halfs per h-row (256 + 8 pad)
#define ZP_LD 17             // f16x4 units per zp col (16 rows + 1 pad)
#define L2E   1.44269504f
#define T2E   2.88539008f

typedef float    f32x4 __attribute__((ext_vector_type(4)));
typedef _Float16 f16x8 __attribute__((ext_vector_type(8)));
typedef _Float16 f16x4 __attribute__((ext_vector_type(4)));

__device__ __forceinline__ float sigf(float x) {          // unscaled (fallback)
    return __builtin_amdgcn_rcpf(1.0f + __expf(-x));
}
__device__ __forceinline__ float tanh_f(float x) {        // unscaled (fallback)
    return 2.0f * __builtin_amdgcn_rcpf(1.0f + __expf(-2.0f * x)) - 1.0f;
}
// pre-scaled forms: input already multiplied by log2e (sig2) / 2*log2e (tanh2)
__device__ __forceinline__ float sig2(float x) {
    return __builtin_amdgcn_rcpf(1.0f + __builtin_amdgcn_exp2f(-x));
}
__device__ __forceinline__ float tanh2(float x) {
    return 2.0f * __builtin_amdgcn_rcpf(1.0f + __builtin_amdgcn_exp2f(-x)) - 1.0f;
}
__device__ __forceinline__ void barrier_lgkm() {
    asm volatile("s_waitcnt lgkmcnt(0)\n\ts_barrier" ::: "memory");
}

// plain B fragment (linear K)
__device__ __forceinline__ f16x8 ld_bfrag(const float* __restrict__ W, int outcol, int ks, int lgrp) {
    const float* p = W + outcol * HDIM + ks * 32 + lgrp * 8;
    float4 a = *(const float4*)p;
    float4 b = *(const float4*)(p + 4);
    f16x8 w = {(_Float16)a.x, (_Float16)a.y, (_Float16)a.z, (_Float16)a.w,
               (_Float16)b.x, (_Float16)b.y, (_Float16)b.z, (_Float16)b.w};
    return w;
}
// scaled B fragment (weights pre-multiplied by s before f16 cast)
__device__ __forceinline__ f16x8 ld_bfrag_s(const float* __restrict__ W, int outcol, int ks, int lgrp, float s) {
    const float* p = W + outcol * HDIM + ks * 32 + lgrp * 8;
    float4 a = *(const float4*)p;
    float4 b = *(const float4*)(p + 4);
    f16x8 w = {(_Float16)(a.x*s), (_Float16)(a.y*s), (_Float16)(a.z*s), (_Float16)(a.w*s),
               (_Float16)(b.x*s), (_Float16)(b.y*s), (_Float16)(b.z*s), (_Float16)(b.w*s)};
    return w;
}

// ---------------- prep: PT4[v][col] = {(xr+bhr)*L2E, (xz+bhz)*L2E, xn*T2E, bhn*T2E} f32x4 ----------------
__global__ void pt_kernel(const float* __restrict__ emb, const float* __restrict__ Wih,
                          const float* __restrict__ bih, const float* __restrict__ bhh,
                          f32x4* __restrict__ PT) {
    int v = blockIdx.x;
    int col = threadIdx.x;               // 0..255
    __shared__ float se[EDIM];
    if (col < EDIM) se[col] = emb[v * EDIM + col];
    __syncthreads();
    const float* wr = Wih + col * EDIM;
    const float* wz = Wih + (col + 256) * EDIM;
    const float* wn = Wih + (col + 512) * EDIM;
    float xr = bih[col]       + bhh[col];
    float xz = bih[col + 256] + bhh[col + 256];
    float xn = bih[col + 512];
    #pragma unroll 4
    for (int e = 0; e < EDIM; ++e) {
        float s = se[e];
        xr += s * wr[e]; xz += s * wz[e]; xn += s * wn[e];
    }
    f32x4 q = {xr * L2E, xz * L2E, xn * T2E, bhh[512 + col] * T2E};
    PT[v * 256 + col] = q;
}

// ===================================================================
// ENCODER (R16 geometry + exp2 prescale + f32 table): 1024 thr / 16
// waves. r,z weights in regs (scaled L2E); n-gate in LDS (scaled T2E).
// ===================================================================
__global__ __launch_bounds__(1024, 4) void enc_kernel(
    const int* __restrict__ x, const f32x4* __restrict__ PT4,
    const float* __restrict__ Whh,
    float* __restrict__ out)
{
    __shared__ _Float16 s_h[2][16 * H_LD];                         // 16896 B
    __shared__ int s_tok[16 * TT];                                 // 8192 B
    __shared__ __attribute__((aligned(16))) _Float16 s_w2[16 * 4096]; // 131072 B

    const int tid  = threadIdx.x;
    const int lane = tid & 63;
    const int wv   = tid >> 6;
    const int l15  = lane & 15;
    const int lgrp = lane >> 4;
    const int bbase = blockIdx.x * 16;
    const int col  = wv * 16 + l15;

    for (int i = tid; i < 16 * TT; i += 1024) s_tok[i] = x[bbase * TT + i];

    // r,z gates -> registers (scaled by L2E)
    f16x8 Breg[2][8];
    #pragma unroll
    for (int g = 0; g < 2; ++g)
        #pragma unroll
        for (int ks = 0; ks < 8; ++ks)
            Breg[g][ks] = ld_bfrag_s(Whh, g * 256 + col, ks, lgrp, L2E);
    // n gate -> LDS (scaled by 2*L2E)
    const int w2base = wv * 4096 + lane * 8;     // shorts
    #pragma unroll
    for (int ks = 0; ks < 8; ++ks) {
        f16x8 w = ld_bfrag_s(Whh, 512 + col, ks, lgrp, T2E);
        *(f16x8*)(s_w2 + w2base + ks * 512) = w;
    }

    float hst[4] = {0.f, 0.f, 0.f, 0.f};

    for (int i = tid; i < 16 * H_LD; i += 1024) s_h[0][i] = (_Float16)0.f;
    __syncthreads();

    int tokp[4];
    #pragma unroll
    for (int j = 0; j < 4; ++j) tokp[j] = s_tok[(lgrp * 4 + j) * TT];

    const f32x4 z4 = {0.f, 0.f, 0.f, 0.f};

    #pragma unroll 1
    for (int t = 0; t < TT; ++t) {
        const _Float16* rh = s_h[t & 1];
        _Float16* wh = s_h[(t + 1) & 1];

        // packed f32x4 gate-input gathers FIRST (hide under MFMA phase)
        f32x4 q[4];
        #pragma unroll
        for (int j = 0; j < 4; ++j) q[j] = PT4[tokp[j] * 256 + col];

        f32x4 a0 = z4, a1 = z4, a2 = z4;
        #pragma unroll
        for (int ks = 0; ks < 8; ++ks) {
            f16x8 a  = *(const f16x8*)(rh + l15 * H_LD + ks * 32 + lgrp * 8);
            f16x8 b2 = *(const f16x8*)(s_w2 + w2base + ks * 512);
            a0 = __builtin_amdgcn_mfma_f32_16x16x32_f16(a, Breg[0][ks], a0, 0, 0, 0);
            a1 = __builtin_amdgcn_mfma_f32_16x16x32_f16(a, Breg[1][ks], a1, 0, 0, 0);
            a2 = __builtin_amdgcn_mfma_f32_16x16x32_f16(a, b2,          a2, 0, 0, 0);
        }

        if (t + 1 < TT) {
            #pragma unroll
            for (int j = 0; j < 4; ++j) tokp[j] = s_tok[(lgrp * 4 + j) * TT + t + 1];
        }

        #pragma unroll
        for (int j = 0; j < 4; ++j) {
            const int row = lgrp * 4 + j;
            f32x4 qq = q[j];
            float rg = sig2(a0[j] + qq[0]);
            float zg = sig2(a1[j] + qq[1]);
            float n  = tanh2(qq[2] + rg * (a2[j] + qq[3]));
            float h  = n + zg * (hst[j] - n);
            hst[j] = h;
            wh[row * H_LD + col] = (_Float16)h;
            if (t == TT - 1) out[(size_t)(bbase + row) * LROW + col] = h;
        }
        barrier_lgkm();
    }
}

// ===================================================================
// MID: dec prologue. mu/lv -> out, z -> h0, zq (PRE-SCALED) -> ws.
// zq = {(r+bhr)*L2E, (z+bhz)*L2E, n*T2E, bhn*T2E} f16x4.
// ===================================================================
__global__ __launch_bounds__(512, 2) void mid_kernel(
    const float* __restrict__ eps,
    const float* __restrict__ mu_W, const float* __restrict__ mu_b,
    const float* __restrict__ lv_W, const float* __restrict__ lv_b,
    const float* __restrict__ di_W, const float* __restrict__ di_b,
    const float* __restrict__ dec_Wih, const float* __restrict__ dec_bih,
    const float* __restrict__ dec_bhh,
    float* __restrict__ out, f16x4* __restrict__ zq_g, float* __restrict__ h0_g)
{
    __shared__ float s_hl[16 * 260];

    const int tid  = threadIdx.x;
    const int bbase = blockIdx.x * 16;

    for (int i = tid; i < 16 * HDIM; i += 512) {
        int m = i >> 8, c = i & 255;
        s_hl[m * 260 + c] = out[(size_t)(bbase + m) * LROW + c];
    }
    __syncthreads();

    float z0 = 0.f, z1 = 0.f;
    {
        const size_t MU_OFF = (size_t)BB * TT * VOCAB;
        const size_t LV_OFF = MU_OFF + (size_t)BB * LDIM;
        #pragma unroll
        for (int oo = 0; oo < 2; ++oo) {
            int o = tid * 2 + oo;
            int m = o >> 6, j = o & 63;
            const float* mwr = mu_W + j * HDIM;
            const float* lwr = lv_W + j * HDIM;
            float am = mu_b[j], al = lv_b[j];
            #pragma unroll 4
            for (int k = 0; k < HDIM; ++k) { float hv = s_hl[m * 260 + k]; am += hv * mwr[k]; al += hv * lwr[k]; }
            size_t bo = (size_t)(bbase + m) * LDIM + j;
            out[MU_OFF + bo] = am;
            out[LV_OFF + bo] = al;
            float zv = am + eps[bo] * __expf(0.5f * al);
            if (oo == 0) z0 = zv; else z1 = zv;
        }
    }
    __syncthreads();
    {
        int o0 = tid * 2;
        s_hl[(o0 >> 6) * 260 + (o0 & 63)] = z0;
        int o1 = o0 + 1;
        s_hl[(o1 >> 6) * 260 + (o1 & 63)] = z1;
    }
    __syncthreads();

    {
        const int gc = tid & 255;
        const int gm2 = tid >> 8;
        float ah[8], ar[8], az[8], an[8];
        float dib = di_b[gc];
        float bir = dec_bih[gc], biz = dec_bih[gc + 256], bin_ = dec_bih[gc + 512];
        #pragma unroll
        for (int i = 0; i < 8; ++i) { ah[i] = dib; ar[i] = bir; az[i] = biz; an[i] = bin_; }
        const float* w0 = di_W + gc * LDIM;
        const float* w1 = dec_Wih + gc * LDIM;
        const float* w2 = dec_Wih + (gc + 256) * LDIM;
        const float* w3 = dec_Wih + (gc + 512) * LDIM;
        #pragma unroll 2
        for (int j = 0; j < LDIM; ++j) {
            float a0 = w0[j], a1 = w1[j], a2 = w2[j], a3 = w3[j];
            #pragma unroll
            for (int i = 0; i < 8; ++i) {
                float q = s_hl[(gm2 + 2 * i) * 260 + j];
                ah[i] += q * a0; ar[i] += q * a1; az[i] += q * a2; an[i] += q * a3;
            }
        }
        float bhr = dec_bhh[gc], bhz = dec_bhh[gc + 256], bhn_c = dec_bhh[gc + 512];
        #pragma unroll
        for (int i = 0; i < 8; ++i) {
            int m = gm2 + 2 * i;
            float th = tanh_f(ah[i]);
            h0_g[(size_t)(bbase + m) * 256 + gc] = th;
            f16x4 q = {(_Float16)((ar[i] + bhr) * L2E), (_Float16)((az[i] + bhz) * L2E),
                       (_Float16)(an[i] * T2E),         (_Float16)(bhn_c * T2E)};
            zq_g[(size_t)(bbase + m) * 256 + gc] = q;
        }
    }
}

// ===================================================================
// DECODER RNN (R16 geometry + exp2 prescale): 1024 thr / 16 waves.
// Breg r,z scaled L2E; n-gate scaled T2E; zq pre-scaled by mid.
// ===================================================================
__global__ __launch_bounds__(1024, 4) void dec_rnn_kernel(
    const float* __restrict__ dec_Whh,
    const f16x4* __restrict__ zq_g, const float* __restrict__ h0_g,
    _Float16* __restrict__ Hbuf)
{
    __shared__ _Float16 s_hb[2][16 * H_LD];   // 16896 B
    __shared__ f16x4 s_zq[256 * ZP_LD];       // 34816 B

    const int tid  = threadIdx.x;
    const int lane = tid & 63;
    const int wv   = tid >> 6;
    const int l15  = lane & 15;
    const int lgrp = lane >> 4;
    const int bbase = blockIdx.x * 16;
    const int col  = wv * 16 + l15;

    for (int i = tid; i < 16 * HDIM; i += 1024) {
        int row = i >> 8, c = i & 255;
        float hv = h0_g[(size_t)(bbase + row) * 256 + c];
        s_hb[0][row * H_LD + c] = (_Float16)hv;
        s_zq[c * ZP_LD + row] = zq_g[(size_t)(bbase + row) * 256 + c];
    }

    f16x8 Breg[3][8];
    #pragma unroll
    for (int g = 0; g < 3; ++g) {
        const float s = (g == 2) ? T2E : L2E;
        #pragma unroll
        for (int ks = 0; ks < 8; ++ks)
            Breg[g][ks] = ld_bfrag_s(dec_Whh, g * 256 + col, ks, lgrp, s);
    }

    float hst[4];
    #pragma unroll
    for (int j = 0; j < 4; ++j)
        hst[j] = h0_g[(size_t)(bbase + lgrp * 4 + j) * 256 + col];
    __syncthreads();

    const f32x4 z4 = {0.f, 0.f, 0.f, 0.f};
    const int crow = tid >> 6;       // 0..15
    const int cseg = lane;           // 0..63 (8B chunks)
    _Float16* hb = Hbuf + ((size_t)(bbase + crow) * TT) * 256 + cseg * 4;
    const int lread = crow * H_LD + cseg * 4;

    #pragma unroll 1
    for (int t = 0; t < TT; ++t) {
        const _Float16* rh = s_hb[t & 1];
        _Float16* wh = s_hb[(t + 1) & 1];

        f32x4 a0 = z4, a1 = z4, a2 = z4;
        #pragma unroll
        for (int ks = 0; ks < 8; ++ks) {
            f16x8 a = *(const f16x8*)(rh + l15 * H_LD + ks * 32 + lgrp * 8);
            a0 = __builtin_amdgcn_mfma_f32_16x16x32_f16(a, Breg[0][ks], a0, 0, 0, 0);
            a1 = __builtin_amdgcn_mfma_f32_16x16x32_f16(a, Breg[1][ks], a1, 0, 0, 0);
            a2 = __builtin_amdgcn_mfma_f32_16x16x32_f16(a, Breg[2][ks], a2, 0, 0, 0);
        }
        #pragma unroll
        for (int j = 0; j < 4; ++j) {
            const int row = lgrp * 4 + j;
            f16x4 q = s_zq[col * ZP_LD + row];
            float rg = sig2(a0[j] + (float)q[0]);
            float zg = sig2(a1[j] + (float)q[1]);
            float n  = tanh2((float)q[2] + rg * (a2[j] + (float)q[3]));
            float h  = n + zg * (hst[j] - n);
            hst[j] = h;
            wh[row * H_LD + col] = (_Float16)h;
        }
        barrier_lgkm();
        *(f16x4*)hb = *(const f16x4*)(wh + lread);
        hb += 256;
    }
}

// ===================================================================
// LOGITS GEMM (R10/R13-verified): LDS-staged LINEAR copy-out.
// ===================================================================
__global__ __launch_bounds__(1024, 4) void logits_kernel(
    const _Float16* __restrict__ Hbuf, const float* __restrict__ out_W,
    const float* __restrict__ out_b, float* __restrict__ out)
{
    __shared__ __attribute__((aligned(16))) unsigned char s_outw[VOCAB * 512]; // 51200 B
    __shared__ __attribute__((aligned(16))) float s_ls[256 * 108];             // 110592 B
    const int tid = threadIdx.x, lane = tid & 63, wv = tid >> 6;
    const int l15 = lane & 15, lgrp = lane >> 4;

    for (int idx = tid; idx < VOCAB * HDIM; idx += 1024) {
        int r = idx >> 8, k = idx & 255;
        _Float16 w = (_Float16)out_W[r * 256 + k];
        *(short*)(s_outw + r * 512 + ((2 * k) ^ ((r & 7) << 4))) = __builtin_bit_cast(short, w);
    }
    __syncthreads();

    float ob[7];
    #pragma unroll
    for (int vt = 0; vt < 7; ++vt) {
        int v = vt * 16 + l15;
        ob[vt] = (v < VOCAB) ? out_b[v] : 0.0f;
    }
    const f32x4 z4 = {0.f, 0.f, 0.f, 0.f};

    #pragma unroll 1
    for (int round = 0; round < 2; ++round) {
        size_t mt = (size_t)blockIdx.x * 32 + round * 16 + wv;
        const _Float16* hrow = Hbuf + (mt * 16 + l15) * 256;
        f32x4 acc[7];
        #pragma unroll
        for (int vt = 0; vt < 7; ++vt) acc[vt] = z4;
        #pragma unroll
        for (int ks = 0; ks < 8; ++ks) {
            f16x8 a = *(const f16x8*)(hrow + ks * 32 + lgrp * 8);
            #pragma unroll
            for (int vt = 0; vt < 7; ++vt) {
                int orow = vt * 16 + l15; if (orow > VOCAB - 1) orow = VOCAB - 1;
                f16x8 wo = *(const f16x8*)(s_outw + orow * 512 + ((ks * 64 + lgrp * 16) ^ ((orow & 7) << 4)));
                acc[vt] = __builtin_amdgcn_mfma_f32_16x16x32_f16(a, wo, acc[vt], 0, 0, 0);
            }
        }
        #pragma unroll
        for (int vt = 0; vt < 7; ++vt) {
            int v = vt * 16 + l15;
            if (v < VOCAB) {
                #pragma unroll
                for (int j = 0; j < 4; ++j)
                    s_ls[(wv * 16 + lgrp * 4 + j) * 108 + v] = acc[vt][j] + ob[vt];
            }
        }
        __syncthreads();
        {
            size_t slabM0 = (size_t)blockIdx.x * 512 + round * 256;
            float* gbase = out + slabM0 * VOCAB;
            for (int c = tid; c < 6400; c += 1024) {
                int r = c / 25, cc = (c % 25) * 4;
                f32x4 vch = *(const f32x4*)(s_ls + r * 108 + cc);
                *(f32x4*)(gbase + (size_t)c * 4) = vch;
            }
        }
        __syncthreads();
    }
}

// ===================================================================
// FALLBACK fused decoder (known-passing, unscaled math) — ws too small.
// ===================================================================
__global__ __launch_bounds__(1024, 4) void dec_fused_kernel(
    const float* __restrict__ eps,
    const float* __restrict__ mu_W, const float* __restrict__ mu_b,
    const float* __restrict__ lv_W, const float* __restrict__ lv_b,
    const float* __restrict__ di_W, const float* __restrict__ di_b,
    const float* __restrict__ dec_Wih, const float* __restrict__ dec_Whh,
    const float* __restrict__ dec_bih, const float* __restrict__ dec_bhh,
    const float* __restrict__ out_W, const float* __restrict__ out_b,
    float* __restrict__ out)
{
    __shared__ _Float16 s_hb[2][16 * H_LD];
    __shared__ f16x4 s_zp[256 * ZP_LD];
    __shared__ __attribute__((aligned(16))) unsigned char s_outw[VOCAB * 512];
    __shared__ float s_hl[16 * 260];

    const int tid  = threadIdx.x;
    const int lane = tid & 63;
    const int wv   = tid >> 6;
    const int l15  = lane & 15;
    const int lgrp = lane >> 4;
    const int bbase = blockIdx.x * 16;
    const int col  = wv * 16 + l15;

    for (int i = tid; i < 16 * HDIM; i += 1024) {
        int m = i >> 8, c = i & 255;
        s_hl[m * 260 + c] = out[(size_t)(bbase + m) * LROW + c];
    }
    for (int idx = tid; idx < VOCAB * HDIM; idx += 1024) {
        int r = idx >> 8, k = idx & 255;
        _Float16 w = (_Float16)out_W[r * 256 + k];
        *(short*)(s_outw + r * 512 + ((2 * k) ^ ((r & 7) << 4))) = __builtin_bit_cast(short, w);
    }

    f16x8 Breg[3][8];
    #pragma unroll
    for (int g = 0; g < 3; ++g)
        #pragma unroll
        for (int ks = 0; ks < 8; ++ks)
            Breg[g][ks] = ld_bfrag(dec_Whh, g * 256 + col, ks, lgrp);
    __syncthreads();

    float zv;
    {
        const size_t MU_OFF = (size_t)BB * TT * VOCAB;
        const size_t LV_OFF = MU_OFF + (size_t)BB * LDIM;
        int m = tid >> 6, j = tid & 63;
        const float* mwr = mu_W + j * HDIM;
        const float* lwr = lv_W + j * HDIM;
        float am = mu_b[j], al = lv_b[j];
        #pragma unroll 4
        for (int k = 0; k < HDIM; ++k) { float hv = s_hl[m * 260 + k]; am += hv * mwr[k]; al += hv * lwr[k]; }
        size_t bo = (size_t)(bbase + m) * LDIM + j;
        out[MU_OFF + bo] = am;
        out[LV_OFF + bo] = al;
        zv = am + eps[bo] * __expf(0.5f * al);
    }
    __syncthreads();
    { int m = tid >> 6, j = tid & 63; s_hl[m * 260 + j] = zv; }
    __syncthreads();

    float th[4];
    {
        const int gc = tid & 255;
        const int gm = tid >> 8;
        float ah[4], ar[4], az[4], an[4];
        float dib = di_b[gc];
        float bir = dec_bih[gc], biz = dec_bih[gc + 256], bin_ = dec_bih[gc + 512];
        #pragma unroll
        for (int i = 0; i < 4; ++i) { ah[i] = dib; ar[i] = bir; az[i] = biz; an[i] = bin_; }
        const float* w0 = di_W + gc * LDIM;
        const float* w1 = dec_Wih + gc * LDIM;
        const float* w2 = dec_Wih + (gc + 256) * LDIM;
        const float* w3 = dec_Wih + (gc + 512) * LDIM;
        #pragma unroll 2
        for (int j = 0; j < LDIM; ++j) {
            float a0 = w0[j], a1 = w1[j], a2 = w2[j], a3 = w3[j];
            #pragma unroll
            for (int i = 0; i < 4; ++i) {
                float q = s_hl[(gm * 4 + i) * 260 + j];
                ah[i] += q * a0; ar[i] += q * a1; az[i] += q * a2; an[i] += q * a3;
            }
        }
        float bhr = dec_bhh[gc], bhz = dec_bhh[gc + 256];
        __syncthreads();
        #pragma unroll
        for (int i = 0; i < 4; ++i) {
            int r = gm * 4 + i;
            th[i] = tanh_f(ah[i]);
            s_hl[r * 260 + gc] = th[i];
            f16x4 q = {(_Float16)(ar[i] + bhr), (_Float16)(az[i] + bhz), (_Float16)an[i], (_Float16)0.f};
            s_zp[gc * ZP_LD + r] = q;
            s_hb[0][r * H_LD + gc] = (_Float16)th[i];
        }
    }
    __syncthreads();

    float hpr[4];
    #pragma unroll
    for (int j = 0; j < 4; ++j) hpr[j] = s_hl[(lgrp * 4 + j) * 260 + col];

    const float bhn = dec_bhh[512 + col];
    const int vcol = wv * 16 + l15;
    const int orow = (vcol < VOCAB) ? vcol : (VOCAB - 1);
    const float ob = (wv < 7 && vcol < VOCAB) ? out_b[vcol] : 0.0f;
    const f32x4 z4 = {0.f, 0.f, 0.f, 0.f};

    #pragma unroll 1
    for (int t = 0; t < TT; ++t) {
        const _Float16* rh = s_hb[t & 1];
        _Float16* wh = s_hb[(t + 1) & 1];

        f32x4 a0 = z4, a1 = z4, a2 = z4, aco = z4;
        #pragma unroll
        for (int ks = 0; ks < 8; ++ks) {
            f16x8 a = *(const f16x8*)(rh + l15 * H_LD + ks * 32 + lgrp * 8);
            a0 = __builtin_amdgcn_mfma_f32_16x16x32_f16(a, Breg[0][ks], a0, 0, 0, 0);
            a1 = __builtin_amdgcn_mfma_f32_16x16x32_f16(a, Breg[1][ks], a1, 0, 0, 0);
            a2 = __builtin_amdgcn_mfma_f32_16x16x32_f16(a, Breg[2][ks], a2, 0, 0, 0);
            if (wv < 7) {
                f16x8 wo = *(const f16x8*)(s_outw + orow * 512 + ((ks * 64 + lgrp * 16) ^ ((orow & 7) << 4)));
                aco = __builtin_amdgcn_mfma_f32_16x16x32_f16(a, wo, aco, 0, 0, 0);
            }
        }
        if (t > 0 && wv < 7 && vcol < VOCAB) {
            size_t base = (size_t)(bbase + lgrp * 4) * LROW + (size_t)(t - 1) * VOCAB + vcol;
            #pragma unroll
            for (int j = 0; j < 4; ++j) out[base + (size_t)j * LROW] = aco[j] + ob;
        }
        #pragma unroll
        for (int j = 0; j < 4; ++j) {
            const int row = lgrp * 4 + j;
            f16x4 q = s_zp[col * ZP_LD + lgrp * 4 + j];
            float rg = sigf(a0[j] + (float)q[0]);
            float zg = sigf(a1[j] + (float)q[1]);
            float n  = tanh_f((float)q[2] + rg * (a2[j] + bhn));
            float h  = n + zg * (hpr[j] - n);
            hpr[j] = h;
            wh[row * H_LD + col] = (_Float16)h;
        }
        barrier_lgkm();
    }

    if (wv < 7) {
        const _Float16* rh = s_hb[0];
        f32x4 aco = z4;
        #pragma unroll
        for (int ks = 0; ks < 8; ++ks) {
            f16x8 a  = *(const f16x8*)(rh + l15 * H_LD + ks * 32 + lgrp * 8);
            f16x8 wo = *(const f16x8*)(s_outw + orow * 512 + ((ks * 64 + lgrp * 16) ^ ((orow & 7) << 4)));
            aco = __builtin_amdgcn_mfma_f32_16x16x32_f16(a, wo, aco, 0, 0, 0);
        }
        if (vcol < VOCAB) {
            size_t base = (size_t)(bbase + lgrp * 4) * LROW + (size_t)(TT - 1) * VOCAB + vcol;
            #pragma unroll
            for (int j = 0; j < 4; ++j) out[base + (size_t)j * LROW] = aco[j] + ob;
        }
    }
}

extern "C" void kernel_launch(void* const* d_in, const int* in_sizes, int n_in,
                              void* d_out, int out_size, void* d_ws, size_t ws_size,
                              hipStream_t stream) {
    const int*   x       = (const int*)  d_in[0];
    const float* eps     = (const float*)d_in[1];
    const float* emb     = (const float*)d_in[2];
    const float* enc_Wih = (const float*)d_in[3];
    const float* enc_Whh = (const float*)d_in[4];
    const float* enc_bih = (const float*)d_in[5];
    const float* enc_bhh = (const float*)d_in[6];
    const float* mu_W    = (const float*)d_in[7];
    const float* mu_b    = (const float*)d_in[8];
    const float* lv_W    = (const float*)d_in[9];
    const float* lv_b    = (const float*)d_in[10];
    const float* di_W    = (const float*)d_in[11];
    const float* di_b    = (const float*)d_in[12];
    const float* dec_Wih = (const float*)d_in[13];
    const float* dec_Whh = (const float*)d_in[14];
    const float* dec_bih = (const float*)d_in[15];
    const float* dec_bhh = (const float*)d_in[16];
    const float* out_W   = (const float*)d_in[17];
    const float* out_b   = (const float*)d_in[18];
    float* out = (float*)d_out;

    // ws layout: PT4 | zq | h0 | Hbuf
    f32x4* PT4 = (f32x4*)d_ws;                                       // 409600 B
    const size_t ZQ_OFF = 409600;
    const size_t H0_OFF = ZQ_OFF + (size_t)BB * 256 * 8;             // zq: 8 MB
    const size_t HB_OFF = H0_OFF + (size_t)BB * 256 * 4;             // h0: 4 MB
    f16x4*    zq_g = (f16x4*)((char*)d_ws + ZQ_OFF);
    float*    h0_g = (float*)((char*)d_ws + H0_OFF);
    _Float16* Hbuf = (_Float16*)((char*)d_ws + HB_OFF);              // 268.4 MB
    const size_t need = HB_OFF + (size_t)BB * TT * 256 * sizeof(_Float16);

    pt_kernel<<<VOCAB, 256, 0, stream>>>(emb, enc_Wih, enc_bih, enc_bhh, PT4);
    enc_kernel<<<BB / 16, 1024, 0, stream>>>(x, PT4, enc_Whh, out);
    if (ws_size >= need) {
        mid_kernel<<<BB / 16, 512, 0, stream>>>(eps, mu_W, mu_b, lv_W, lv_b,
            di_W, di_b, dec_Wih, dec_bih, dec_bhh, out, zq_g, h0_g);
        dec_rnn_kernel<<<BB / 16, 1024, 0, stream>>>(dec_Whh, zq_g, h0_g, Hbuf);
        logits_kernel<<<(BB * TT / 16) / 32, 1024, 0, stream>>>(Hbuf, out_W, out_b, out);
    } else {
        dec_fused_kernel<<<BB / 16, 1024, 0, stream>>>(eps, mu_W, mu_b, lv_W, lv_b,
            di_W, di_b, dec_Wih, dec_Whh, dec_bih, dec_bhh, out_W, out_b, out);
    }
}